// Round 7
// baseline (239.530 us; speedup 1.0000x reference)
//
#include <hip/hip_runtime.h>
#include <hip/hip_bf16.h>

// AttnBlock: B=8, C=512, N=2048, G=32.
// All GEMMs NT: Out[m][n] = sum_k A[m][k] * Bt[n][k].
// R7 = R6 with grid-size fix (v/proj: 256 blocks, not 512 -> OOB writes gone).
// Fabric-BW theory: batch->XCD pinning (blockIdx%8 == batch, by-major tile order
// within XCD so co-resident blocks share panels -> re-reads hit the 4MB per-XCD L2
// instead of ~6.3TB/s fabric) + nontemporal stores (don't evict staged panels).

typedef __attribute__((ext_vector_type(8))) short short8;
typedef __attribute__((ext_vector_type(4))) float f32x4;
typedef unsigned short u16;

#define BK 64

__device__ __forceinline__ u16 f2bf(float f) {
  __hip_bfloat16 h = __float2bfloat16(f);
  return __builtin_bit_cast(u16, h);
}
__device__ __forceinline__ float bf2f(u16 u) {
  return __uint_as_float(((unsigned)u) << 16);
}

__device__ __forceinline__ void gload_lds16(const void* g, void* l) {
  __builtin_amdgcn_global_load_lds((const __attribute__((address_space(1))) void*)g,
                                   (__attribute__((address_space(3))) void*)l, 16, 0, 0);
}

// MODE 0: bf16 out = acc + bias[col]
// MODE 1: bf16 out = acc + bias[row]
// MODE 2: bf16 out = acc * scale
// MODE 3: bf16 out = acc
// MODE 4: f32  out = acc + bias[row] + resid[b*sRes + row*ldo + col]
// Grid: 1-D, gid = t*8 + b;  t = by*GX + bx;  m0 = by*BM + b*mOffB; n0 = bx*BN.
template <int MODE, int BM_, int BN_>
__global__ __launch_bounds__(512, 2) void gemm6(
    const u16* __restrict__ A, const u16* __restrict__ Bt, void* __restrict__ OutV,
    const float* __restrict__ bias, const float* __restrict__ resid,
    int K, int lda, int ldb, int ldo, int GX, int mOffB,
    long sA, long sBt, long sOut, long sRes, float scale) {
  constexpr int WM = (BN_ == 256) ? 2 : 4;  // wave grid M
  constexpr int WN = 8 / WM;                // wave grid N
  constexpr int WROWS = BM_ / WM;           // 128 or 64
  constexpr int WCOLS = BN_ / WN;           // 64
  constexpr int MF = WROWS / 16;            // 8 or 4
  constexpr int NF = WCOLS / 16;            // 4
  constexpr int NPH = MF / 2;               // 4 or 2 phases, 16 MFMA each
  constexpr int A_EL = BM_ * BK;
  constexpr int B_EL = BN_ * BK;
  constexpr int SLOT = A_EL + B_EL;
  constexpr int ACH = BM_ / 64;             // A 16B-chunks per thread per K-step
  constexpr int BCH = BN_ / 64;

  __shared__ __align__(16) u16 lds[2 * SLOT];

  const int gid = blockIdx.x;
  const int b = gid & 7;          // batch == XCD (presumed round-robin dispatch)
  const int t = gid >> 3;
  const int bx = t % GX;
  const int by = t / GX;
  const u16* Ab = A + (long)b * sA;
  const u16* Bb = Bt + (long)b * sBt;
  const int tid = threadIdx.x;
  const int lane = tid & 63;
  const int wid = tid >> 6;
  const int wr = wid / WN;
  const int wc = wid % WN;
  const int m0 = by * BM_ + b * mOffB;
  const int n0 = bx * BN_;
  const int l15 = lane & 15;
  const int lhi = lane >> 4;
  const int sl = (l15 & 7) << 4;  // read-side XOR swizzle (bytes); row stride 128B

  f32x4 acc[MF][NF];
#pragma unroll
  for (int i = 0; i < MF; ++i)
#pragma unroll
    for (int j = 0; j < NF; ++j) acc[i][j] = (f32x4){0.f, 0.f, 0.f, 0.f};

  const int T = K / BK;

  auto stage = [&](int kt, int slot) {
    u16* As = lds + slot * SLOT;
    u16* Bs = As + A_EL;
    const int ks = kt * BK;
#pragma unroll
    for (int i = 0; i < ACH; ++i) {
      const int c = tid + i * 512;
      const int row = c >> 3;
      const int kbs = ((c & 7) << 4) ^ ((row & 7) << 4);
      gload_lds16(Ab + (long)(m0 + row) * lda + ks + (kbs >> 1), (void*)(As + c * 8));
    }
#pragma unroll
    for (int i = 0; i < BCH; ++i) {
      const int c = tid + i * 512;
      const int row = c >> 3;
      const int kbs = ((c & 7) << 4) ^ ((row & 7) << 4);
      gload_lds16(Bb + (long)(n0 + row) * ldb + ks + (kbs >> 1), (void*)(Bs + c * 8));
    }
  };

  stage(0, 0);

  for (int kt = 0; kt < T; ++kt) {
    const int s = kt & 1;
    asm volatile("s_waitcnt vmcnt(0)" ::: "memory");
    __builtin_amdgcn_sched_barrier(0);
    __builtin_amdgcn_s_barrier();
    __builtin_amdgcn_sched_barrier(0);
    if (kt + 1 < T) stage(kt + 1, s ^ 1);

    const u16* A_ = lds + s * SLOT;
    const u16* B_ = A_ + A_EL;
    short8 bfrag[NF][2];
#pragma unroll
    for (int p = 0; p < NPH; ++p) {
      if (p == 0) {
#pragma unroll
        for (int nf = 0; nf < NF; ++nf)
#pragma unroll
          for (int kh = 0; kh < 2; ++kh)
            bfrag[nf][kh] = *(const short8*)(B_ + (wc * WCOLS + nf * 16 + l15) * BK +
                                             (((kh * 64 + lhi * 16) ^ sl) >> 1));
      }
      short8 af[2][2];
#pragma unroll
      for (int i = 0; i < 2; ++i)
#pragma unroll
        for (int kh = 0; kh < 2; ++kh)
          af[i][kh] = *(const short8*)(A_ + (wr * WROWS + (2 * p + i) * 16 + l15) * BK +
                                       (((kh * 64 + lhi * 16) ^ sl) >> 1));
      __builtin_amdgcn_sched_barrier(0);
      __builtin_amdgcn_s_barrier();
      asm volatile("s_waitcnt lgkmcnt(0)" ::: "memory");
      __builtin_amdgcn_sched_barrier(0);
      __builtin_amdgcn_s_setprio(1);
#pragma unroll
      for (int kh = 0; kh < 2; ++kh)
#pragma unroll
        for (int i = 0; i < 2; ++i)
#pragma unroll
          for (int nf = 0; nf < NF; ++nf)
            acc[2 * p + i][nf] = __builtin_amdgcn_mfma_f32_16x16x32_bf16(
                af[i][kh], bfrag[nf][kh], acc[2 * p + i][nf], 0, 0, 0);
      __builtin_amdgcn_s_setprio(0);
      __builtin_amdgcn_sched_barrier(0);
      __builtin_amdgcn_s_barrier();
      __builtin_amdgcn_sched_barrier(0);
    }
  }

  // epilogue: D row=(lane>>4)*4+reg (m dim), col=lane&15 (n dim); nontemporal stores
  const int rbase = m0 + wr * WROWS + lhi * 4;
  const int cbase = n0 + wc * WCOLS + l15;
#pragma unroll
  for (int mf = 0; mf < MF; ++mf) {
#pragma unroll
    for (int nf = 0; nf < NF; ++nf) {
#pragma unroll
      for (int i = 0; i < 4; ++i) {
        const int row = rbase + mf * 16 + i;
        const int col = cbase + nf * 16;
        const long oidx = (long)b * sOut + (long)row * ldo + col;
        const float v = acc[mf][nf][i];
        if (MODE == 0) {
          __builtin_nontemporal_store(f2bf(v + bias[col]), (u16*)OutV + oidx);
        } else if (MODE == 1) {
          __builtin_nontemporal_store(f2bf(v + bias[row]), (u16*)OutV + oidx);
        } else if (MODE == 2) {
          __builtin_nontemporal_store(f2bf(v * scale), (u16*)OutV + oidx);
        } else if (MODE == 3) {
          __builtin_nontemporal_store(f2bf(v), (u16*)OutV + oidx);
        } else {
          const float r = resid[(long)b * sRes + (long)row * ldo + col];
          __builtin_nontemporal_store(v + bias[row] + r, (float*)OutV + oidx);
        }
      }
    }
  }
}

// per-(b,g) mean/rstd over contiguous 16*2048 = 32768 floats
__global__ __launch_bounds__(256) void gn_stats(const float* __restrict__ x,
                                                float* __restrict__ stats) {
  const int bg = blockIdx.x;
  const float4* p4 = (const float4*)(x + (long)bg * 32768);
  float s = 0.f, ss = 0.f;
  for (int i = threadIdx.x; i < 8192; i += 256) {
    const float4 u = p4[i];
    s += (u.x + u.y) + (u.z + u.w);
    ss += (u.x * u.x + u.y * u.y) + (u.z * u.z + u.w * u.w);
  }
#pragma unroll
  for (int off = 32; off > 0; off >>= 1) {
    s += __shfl_xor(s, off, 64);
    ss += __shfl_xor(ss, off, 64);
  }
  __shared__ float rs[4], rss[4];
  const int lane = threadIdx.x & 63, wid = threadIdx.x >> 6;
  if (lane == 0) { rs[wid] = s; rss[wid] = ss; }
  __syncthreads();
  if (threadIdx.x == 0) {
    s = rs[0] + rs[1] + rs[2] + rs[3];
    ss = rss[0] + rss[1] + rss[2] + rss[3];
    const float mean = s * (1.f / 32768.f);
    const float var = ss * (1.f / 32768.f) - mean * mean;
    stats[bg * 2] = mean;
    stats[bg * 2 + 1] = rsqrtf(var + 1e-6f);
  }
}

// normalize + affine, write hT[b][n][c] bf16 (64x64 LDS-tiled transpose)
__global__ __launch_bounds__(256) void gn_apply_t(
    const float* __restrict__ x, const float* __restrict__ stats,
    const float* __restrict__ gamma, const float* __restrict__ beta,
    u16* __restrict__ hT) {
  const int b = blockIdx.z, c0 = blockIdx.y * 64, n0 = blockIdx.x * 64;
  __shared__ u16 t[64][72];
  const int tid = threadIdx.x;
  const float* px = x + ((long)b * 512 + c0) * 2048 + n0;
#pragma unroll
  for (int i = 0; i < 4; ++i) {
    const int idx = tid + i * 256;  // 1024 float4 = 64 rows x 16
    const int r = idx >> 4, q4 = (idx & 15) * 4;
    const float4 u = *(const float4*)(px + (long)r * 2048 + q4);
    const int c = c0 + r, g = c >> 4;
    const float mean = stats[(b * 32 + g) * 2];
    const float rstd = stats[(b * 32 + g) * 2 + 1];
    const float ga = gamma[c] * rstd;
    const float be = beta[c] - mean * ga;
    t[r][q4 + 0] = f2bf(u.x * ga + be);
    t[r][q4 + 1] = f2bf(u.y * ga + be);
    t[r][q4 + 2] = f2bf(u.z * ga + be);
    t[r][q4 + 3] = f2bf(u.w * ga + be);
  }
  __syncthreads();
#pragma unroll
  for (int i = 0; i < 2; ++i) {
    const int idx = tid + i * 256;  // 512 chunks = 64 n-rows x 8
    const int nr = idx >> 3, cc = (idx & 7) * 8;
    short8 w;
#pragma unroll
    for (int j = 0; j < 8; ++j) w[j] = (short)t[cc + j][nr];
    *(short8*)(hT + ((long)b * 2048 + n0 + nr) * 512 + c0 + cc) = w;
  }
}

// row softmax in place on bf16 S; gid = r*8 + b, row = b*2048 + r (XCD-pinned)
__global__ __launch_bounds__(256) void softmax_rows(u16* __restrict__ S) {
  const int gid = blockIdx.x;
  const long row = (long)(gid & 7) * 2048 + (gid >> 3);
  u16* p = S + row * 2048;
  const int tid = threadIdx.x;
  const int lane = tid & 63, wid = tid >> 6;
  const short8 raw = *(const short8*)(p + tid * 8);
  float v[8];
#pragma unroll
  for (int j = 0; j < 8; ++j) v[j] = bf2f((u16)raw[j]);
  float m = v[0];
#pragma unroll
  for (int j = 1; j < 8; ++j) m = fmaxf(m, v[j]);
#pragma unroll
  for (int off = 32; off > 0; off >>= 1) m = fmaxf(m, __shfl_xor(m, off, 64));
  __shared__ float redm[4], reds[4];
  if (lane == 0) redm[wid] = m;
  __syncthreads();
  m = fmaxf(fmaxf(redm[0], redm[1]), fmaxf(redm[2], redm[3]));
  float e[8];
  float s = 0.f;
#pragma unroll
  for (int j = 0; j < 8; ++j) {
    e[j] = __expf(v[j] - m);
    s += e[j];
  }
#pragma unroll
  for (int off = 32; off > 0; off >>= 1) s += __shfl_xor(s, off, 64);
  if (lane == 0) reds[wid] = s;
  __syncthreads();
  s = reds[0] + reds[1] + reds[2] + reds[3];
  const float inv = 1.f / s;
  short8 o;
#pragma unroll
  for (int j = 0; j < 8; ++j) o[j] = (short)f2bf(e[j] * inv);
  __builtin_nontemporal_store(o, (short8*)(p + tid * 8));
}

// convert the 4 fp32 512x512 weights to bf16 (contiguous -> wq|wk|wv|wp)
__global__ __launch_bounds__(256) void cvt_w(const float* __restrict__ w0,
                                             const float* __restrict__ w1,
                                             const float* __restrict__ w2,
                                             const float* __restrict__ w3,
                                             u16* __restrict__ out) {
  const int z = blockIdx.y;
  const float* src = (z == 0) ? w0 : (z == 1) ? w1 : (z == 2) ? w2 : w3;
  const int i = blockIdx.x * 256 + threadIdx.x;
  out[(long)z * 262144 + i] = f2bf(src[i]);
}

// concat bq|bk -> bqk[1024]
__global__ __launch_bounds__(256) void cvt_bias(const float* __restrict__ bq,
                                                const float* __restrict__ bk,
                                                float* __restrict__ bqk) {
  const int i = blockIdx.x * 256 + threadIdx.x;
  bqk[i] = (i < 512) ? bq[i] : bk[i - 512];
}

extern "C" void kernel_launch(void* const* d_in, const int* in_sizes, int n_in,
                              void* d_out, int out_size, void* d_ws, size_t ws_size,
                              hipStream_t stream) {
  const float* x = (const float*)d_in[0];
  const float* gs = (const float*)d_in[1];
  const float* gb = (const float*)d_in[2];
  const float* wq = (const float*)d_in[3];
  const float* bq = (const float*)d_in[4];
  const float* wk = (const float*)d_in[5];
  const float* bk = (const float*)d_in[6];
  const float* wv = (const float*)d_in[7];
  const float* bv = (const float*)d_in[8];
  const float* wp = (const float*)d_in[9];
  const float* bp = (const float*)d_in[10];

  char* ws = (char*)d_ws;
  float* stats = (float*)ws;               // 2 KB
  float* bqk = (float*)(ws + 4096);        // 4 KB
  u16* hT = (u16*)(ws + 8192);             // [16384, 512] bf16, 16 MB  (rows = b*2048+n)
  u16* qkT = hT + 8388608;                 // [16384, 1024] bf16, 32 MB (q cols 0-511, k 512-1023)
  u16* vv = qkT + 16777216;                // [B, 512, 2048] bf16, 16 MB
  u16* S = vv + 8388608;                   // [B, 2048, 2048] bf16, 64 MB
  u16* wb = S + 33554432;                  // wq|wk|wv|wp bf16, 2 MB
  u16* attnT = hT;                         // alias: hT dead after qk + v GEMMs
  float* out = (float*)d_out;

  cvt_w<<<dim3(1024, 4, 1), 256, 0, stream>>>(wq, wk, wv, wp, wb);
  cvt_bias<<<dim3(4), 256, 0, stream>>>(bq, bk, bqk);
  gn_stats<<<dim3(256), 256, 0, stream>>>(x, stats);
  gn_apply_t<<<dim3(32, 8, 8), 256, 0, stream>>>(x, stats, gs, gb, hT);

  // qkT[r][o] = sum_c hT[r][c]*Wqk[o][c] + bqk[o];  per-b tiles 8m x 4n = 32 -> 256 blocks
  gemm6<0, 256, 256><<<dim3(256), 512, 0, stream>>>(
      hT, wb, qkT, bqk, nullptr, 512, 512, 512, 1024, /*GX*/4, /*mOffB*/2048, 0, 0, 0, 0, 0.f);
  // v[b][o][n] = sum_c Wv[o][c]*hT[b][n][c] + bv[o];  per-b 2m x 16n = 32 -> 256 blocks
  gemm6<1, 256, 128><<<dim3(256), 512, 0, stream>>>(
      wb + 524288, hT, vv, bv, nullptr, 512, 512, 512, 2048, 16, 0, 0, 1048576, 1048576, 0, 0.f);
  // S[b][i][j] = scale * sum_c q[b][i][c]*k[b][j][c];  per-b 8m x 8n = 64 -> 512 blocks
  gemm6<2, 256, 256><<<dim3(512), 512, 0, stream>>>(
      qkT, qkT + 512, S, nullptr, nullptr, 512, 1024, 1024, 2048, 8, 0, 2097152, 2097152,
      4194304, 0, 0.04419417382415922f);
  softmax_rows<<<dim3(16384), 256, 0, stream>>>(S);
  // attnT[b][i][c] = sum_j P[b][i][j]*v[b][c][j];  per-b 8m x 4n = 32 -> 256 blocks
  gemm6<3, 256, 128><<<dim3(256), 512, 0, stream>>>(
      S, vv, attnT, nullptr, nullptr, 2048, 2048, 2048, 512, 4, 0, 4194304, 1048576,
      1048576, 0, 0.f);
  // out[b][o][n] = sum_c Wp[o][c]*attnT[b][n][c] + bp[o] + x[b][o][n];  per-b 2m x 16n = 32 -> 256
  gemm6<4, 256, 128><<<dim3(256), 512, 0, stream>>>(
      wb + 786432, attnT, out, bp, x, 512, 512, 512, 2048, 16, 0, 0, 1048576, 1048576,
      1048576, 0.f);
}

// Round 8
// 188.680 us; speedup vs baseline: 1.2695x; 1.2695x over previous
//
#include <hip/hip_runtime.h>
#include <hip/hip_bf16.h>

// AttnBlock: B=8, C=512, N=2048, G=32.
// All GEMMs NT: Out[m][n] = sum_k A[m][k] * Bt[n][k].
// R8 = R7 with nontemporal stores reverted (NT caused 2-4x write amplification:
// WRITE_SIZE 65->130-135MB, partial-line HBM writes). Keep batch->XCD pinning
// (confirmed: FETCH_SIZE 74->17MB, panel re-reads served by per-XCD L2).

typedef __attribute__((ext_vector_type(8))) short short8;
typedef __attribute__((ext_vector_type(4))) float f32x4;
typedef unsigned short u16;

#define BK 64

__device__ __forceinline__ u16 f2bf(float f) {
  __hip_bfloat16 h = __float2bfloat16(f);
  return __builtin_bit_cast(u16, h);
}
__device__ __forceinline__ float bf2f(u16 u) {
  return __uint_as_float(((unsigned)u) << 16);
}

__device__ __forceinline__ void gload_lds16(const void* g, void* l) {
  __builtin_amdgcn_global_load_lds((const __attribute__((address_space(1))) void*)g,
                                   (__attribute__((address_space(3))) void*)l, 16, 0, 0);
}

// MODE 0: bf16 out = acc + bias[col]
// MODE 1: bf16 out = acc + bias[row]
// MODE 2: bf16 out = acc * scale
// MODE 3: bf16 out = acc
// MODE 4: f32  out = acc + bias[row] + resid[b*sRes + row*ldo + col]
// Grid: 1-D, gid = t*8 + b;  t = by*GX + bx;  m0 = by*BM + b*mOffB; n0 = bx*BN.
template <int MODE, int BM_, int BN_>
__global__ __launch_bounds__(512, 2) void gemm6(
    const u16* __restrict__ A, const u16* __restrict__ Bt, void* __restrict__ OutV,
    const float* __restrict__ bias, const float* __restrict__ resid,
    int K, int lda, int ldb, int ldo, int GX, int mOffB,
    long sA, long sBt, long sOut, long sRes, float scale) {
  constexpr int WM = (BN_ == 256) ? 2 : 4;  // wave grid M
  constexpr int WN = 8 / WM;                // wave grid N
  constexpr int WROWS = BM_ / WM;           // 128 or 64
  constexpr int WCOLS = BN_ / WN;           // 64
  constexpr int MF = WROWS / 16;            // 8 or 4
  constexpr int NF = WCOLS / 16;            // 4
  constexpr int NPH = MF / 2;               // 4 or 2 phases, 16 MFMA each
  constexpr int A_EL = BM_ * BK;
  constexpr int B_EL = BN_ * BK;
  constexpr int SLOT = A_EL + B_EL;
  constexpr int ACH = BM_ / 64;             // A 16B-chunks per thread per K-step
  constexpr int BCH = BN_ / 64;

  __shared__ __align__(16) u16 lds[2 * SLOT];

  const int gid = blockIdx.x;
  const int b = gid & 7;          // batch == XCD (round-robin dispatch)
  const int t = gid >> 3;
  const int bx = t % GX;
  const int by = t / GX;
  const u16* Ab = A + (long)b * sA;
  const u16* Bb = Bt + (long)b * sBt;
  const int tid = threadIdx.x;
  const int lane = tid & 63;
  const int wid = tid >> 6;
  const int wr = wid / WN;
  const int wc = wid % WN;
  const int m0 = by * BM_ + b * mOffB;
  const int n0 = bx * BN_;
  const int l15 = lane & 15;
  const int lhi = lane >> 4;
  const int sl = (l15 & 7) << 4;  // read-side XOR swizzle (bytes); row stride 128B

  f32x4 acc[MF][NF];
#pragma unroll
  for (int i = 0; i < MF; ++i)
#pragma unroll
    for (int j = 0; j < NF; ++j) acc[i][j] = (f32x4){0.f, 0.f, 0.f, 0.f};

  const int T = K / BK;

  auto stage = [&](int kt, int slot) {
    u16* As = lds + slot * SLOT;
    u16* Bs = As + A_EL;
    const int ks = kt * BK;
#pragma unroll
    for (int i = 0; i < ACH; ++i) {
      const int c = tid + i * 512;
      const int row = c >> 3;
      const int kbs = ((c & 7) << 4) ^ ((row & 7) << 4);
      gload_lds16(Ab + (long)(m0 + row) * lda + ks + (kbs >> 1), (void*)(As + c * 8));
    }
#pragma unroll
    for (int i = 0; i < BCH; ++i) {
      const int c = tid + i * 512;
      const int row = c >> 3;
      const int kbs = ((c & 7) << 4) ^ ((row & 7) << 4);
      gload_lds16(Bb + (long)(n0 + row) * ldb + ks + (kbs >> 1), (void*)(Bs + c * 8));
    }
  };

  stage(0, 0);

  for (int kt = 0; kt < T; ++kt) {
    const int s = kt & 1;
    asm volatile("s_waitcnt vmcnt(0)" ::: "memory");
    __builtin_amdgcn_sched_barrier(0);
    __builtin_amdgcn_s_barrier();
    __builtin_amdgcn_sched_barrier(0);
    if (kt + 1 < T) stage(kt + 1, s ^ 1);

    const u16* A_ = lds + s * SLOT;
    const u16* B_ = A_ + A_EL;
    short8 bfrag[NF][2];
#pragma unroll
    for (int p = 0; p < NPH; ++p) {
      if (p == 0) {
#pragma unroll
        for (int nf = 0; nf < NF; ++nf)
#pragma unroll
          for (int kh = 0; kh < 2; ++kh)
            bfrag[nf][kh] = *(const short8*)(B_ + (wc * WCOLS + nf * 16 + l15) * BK +
                                             (((kh * 64 + lhi * 16) ^ sl) >> 1));
      }
      short8 af[2][2];
#pragma unroll
      for (int i = 0; i < 2; ++i)
#pragma unroll
        for (int kh = 0; kh < 2; ++kh)
          af[i][kh] = *(const short8*)(A_ + (wr * WROWS + (2 * p + i) * 16 + l15) * BK +
                                       (((kh * 64 + lhi * 16) ^ sl) >> 1));
      __builtin_amdgcn_sched_barrier(0);
      __builtin_amdgcn_s_barrier();
      asm volatile("s_waitcnt lgkmcnt(0)" ::: "memory");
      __builtin_amdgcn_sched_barrier(0);
      __builtin_amdgcn_s_setprio(1);
#pragma unroll
      for (int kh = 0; kh < 2; ++kh)
#pragma unroll
        for (int i = 0; i < 2; ++i)
#pragma unroll
          for (int nf = 0; nf < NF; ++nf)
            acc[2 * p + i][nf] = __builtin_amdgcn_mfma_f32_16x16x32_bf16(
                af[i][kh], bfrag[nf][kh], acc[2 * p + i][nf], 0, 0, 0);
      __builtin_amdgcn_s_setprio(0);
      __builtin_amdgcn_sched_barrier(0);
      __builtin_amdgcn_s_barrier();
      __builtin_amdgcn_sched_barrier(0);
    }
  }

  // epilogue: D row=(lane>>4)*4+reg (m dim), col=lane&15 (n dim); plain stores (L2-merged)
  const int rbase = m0 + wr * WROWS + lhi * 4;
  const int cbase = n0 + wc * WCOLS + l15;
#pragma unroll
  for (int mf = 0; mf < MF; ++mf) {
#pragma unroll
    for (int nf = 0; nf < NF; ++nf) {
#pragma unroll
      for (int i = 0; i < 4; ++i) {
        const int row = rbase + mf * 16 + i;
        const int col = cbase + nf * 16;
        const long oidx = (long)b * sOut + (long)row * ldo + col;
        const float v = acc[mf][nf][i];
        if (MODE == 0) {
          ((u16*)OutV)[oidx] = f2bf(v + bias[col]);
        } else if (MODE == 1) {
          ((u16*)OutV)[oidx] = f2bf(v + bias[row]);
        } else if (MODE == 2) {
          ((u16*)OutV)[oidx] = f2bf(v * scale);
        } else if (MODE == 3) {
          ((u16*)OutV)[oidx] = f2bf(v);
        } else {
          const float r = resid[(long)b * sRes + (long)row * ldo + col];
          ((float*)OutV)[oidx] = v + bias[row] + r;
        }
      }
    }
  }
}

// per-(b,g) mean/rstd over contiguous 16*2048 = 32768 floats
__global__ __launch_bounds__(256) void gn_stats(const float* __restrict__ x,
                                                float* __restrict__ stats) {
  const int bg = blockIdx.x;
  const float4* p4 = (const float4*)(x + (long)bg * 32768);
  float s = 0.f, ss = 0.f;
  for (int i = threadIdx.x; i < 8192; i += 256) {
    const float4 u = p4[i];
    s += (u.x + u.y) + (u.z + u.w);
    ss += (u.x * u.x + u.y * u.y) + (u.z * u.z + u.w * u.w);
  }
#pragma unroll
  for (int off = 32; off > 0; off >>= 1) {
    s += __shfl_xor(s, off, 64);
    ss += __shfl_xor(ss, off, 64);
  }
  __shared__ float rs[4], rss[4];
  const int lane = threadIdx.x & 63, wid = threadIdx.x >> 6;
  if (lane == 0) { rs[wid] = s; rss[wid] = ss; }
  __syncthreads();
  if (threadIdx.x == 0) {
    s = rs[0] + rs[1] + rs[2] + rs[3];
    ss = rss[0] + rss[1] + rss[2] + rss[3];
    const float mean = s * (1.f / 32768.f);
    const float var = ss * (1.f / 32768.f) - mean * mean;
    stats[bg * 2] = mean;
    stats[bg * 2 + 1] = rsqrtf(var + 1e-6f);
  }
}

// normalize + affine, write hT[b][n][c] bf16 (64x64 LDS-tiled transpose)
__global__ __launch_bounds__(256) void gn_apply_t(
    const float* __restrict__ x, const float* __restrict__ stats,
    const float* __restrict__ gamma, const float* __restrict__ beta,
    u16* __restrict__ hT) {
  const int b = blockIdx.z, c0 = blockIdx.y * 64, n0 = blockIdx.x * 64;
  __shared__ u16 t[64][72];
  const int tid = threadIdx.x;
  const float* px = x + ((long)b * 512 + c0) * 2048 + n0;
#pragma unroll
  for (int i = 0; i < 4; ++i) {
    const int idx = tid + i * 256;  // 1024 float4 = 64 rows x 16
    const int r = idx >> 4, q4 = (idx & 15) * 4;
    const float4 u = *(const float4*)(px + (long)r * 2048 + q4);
    const int c = c0 + r, g = c >> 4;
    const float mean = stats[(b * 32 + g) * 2];
    const float rstd = stats[(b * 32 + g) * 2 + 1];
    const float ga = gamma[c] * rstd;
    const float be = beta[c] - mean * ga;
    t[r][q4 + 0] = f2bf(u.x * ga + be);
    t[r][q4 + 1] = f2bf(u.y * ga + be);
    t[r][q4 + 2] = f2bf(u.z * ga + be);
    t[r][q4 + 3] = f2bf(u.w * ga + be);
  }
  __syncthreads();
#pragma unroll
  for (int i = 0; i < 2; ++i) {
    const int idx = tid + i * 256;  // 512 chunks = 64 n-rows x 8
    const int nr = idx >> 3, cc = (idx & 7) * 8;
    short8 w;
#pragma unroll
    for (int j = 0; j < 8; ++j) w[j] = (short)t[cc + j][nr];
    *(short8*)(hT + ((long)b * 2048 + n0 + nr) * 512 + c0 + cc) = w;
  }
}

// row softmax in place on bf16 S; gid = r*8 + b, row = b*2048 + r (XCD-pinned)
__global__ __launch_bounds__(256) void softmax_rows(u16* __restrict__ S) {
  const int gid = blockIdx.x;
  const long row = (long)(gid & 7) * 2048 + (gid >> 3);
  u16* p = S + row * 2048;
  const int tid = threadIdx.x;
  const int lane = tid & 63, wid = tid >> 6;
  const short8 raw = *(const short8*)(p + tid * 8);
  float v[8];
#pragma unroll
  for (int j = 0; j < 8; ++j) v[j] = bf2f((u16)raw[j]);
  float m = v[0];
#pragma unroll
  for (int j = 1; j < 8; ++j) m = fmaxf(m, v[j]);
#pragma unroll
  for (int off = 32; off > 0; off >>= 1) m = fmaxf(m, __shfl_xor(m, off, 64));
  __shared__ float redm[4], reds[4];
  if (lane == 0) redm[wid] = m;
  __syncthreads();
  m = fmaxf(fmaxf(redm[0], redm[1]), fmaxf(redm[2], redm[3]));
  float e[8];
  float s = 0.f;
#pragma unroll
  for (int j = 0; j < 8; ++j) {
    e[j] = __expf(v[j] - m);
    s += e[j];
  }
#pragma unroll
  for (int off = 32; off > 0; off >>= 1) s += __shfl_xor(s, off, 64);
  if (lane == 0) reds[wid] = s;
  __syncthreads();
  s = reds[0] + reds[1] + reds[2] + reds[3];
  const float inv = 1.f / s;
  short8 o;
#pragma unroll
  for (int j = 0; j < 8; ++j) o[j] = (short)f2bf(e[j] * inv);
  *(short8*)(p + tid * 8) = o;
}

// convert the 4 fp32 512x512 weights to bf16 (contiguous -> wq|wk|wv|wp)
__global__ __launch_bounds__(256) void cvt_w(const float* __restrict__ w0,
                                             const float* __restrict__ w1,
                                             const float* __restrict__ w2,
                                             const float* __restrict__ w3,
                                             u16* __restrict__ out) {
  const int z = blockIdx.y;
  const float* src = (z == 0) ? w0 : (z == 1) ? w1 : (z == 2) ? w2 : w3;
  const int i = blockIdx.x * 256 + threadIdx.x;
  out[(long)z * 262144 + i] = f2bf(src[i]);
}

// concat bq|bk -> bqk[1024]
__global__ __launch_bounds__(256) void cvt_bias(const float* __restrict__ bq,
                                                const float* __restrict__ bk,
                                                float* __restrict__ bqk) {
  const int i = blockIdx.x * 256 + threadIdx.x;
  bqk[i] = (i < 512) ? bq[i] : bk[i - 512];
}

extern "C" void kernel_launch(void* const* d_in, const int* in_sizes, int n_in,
                              void* d_out, int out_size, void* d_ws, size_t ws_size,
                              hipStream_t stream) {
  const float* x = (const float*)d_in[0];
  const float* gs = (const float*)d_in[1];
  const float* gb = (const float*)d_in[2];
  const float* wq = (const float*)d_in[3];
  const float* bq = (const float*)d_in[4];
  const float* wk = (const float*)d_in[5];
  const float* bk = (const float*)d_in[6];
  const float* wv = (const float*)d_in[7];
  const float* bv = (const float*)d_in[8];
  const float* wp = (const float*)d_in[9];
  const float* bp = (const float*)d_in[10];

  char* ws = (char*)d_ws;
  float* stats = (float*)ws;               // 2 KB
  float* bqk = (float*)(ws + 4096);        // 4 KB
  u16* hT = (u16*)(ws + 8192);             // [16384, 512] bf16, 16 MB  (rows = b*2048+n)
  u16* qkT = hT + 8388608;                 // [16384, 1024] bf16, 32 MB (q cols 0-511, k 512-1023)
  u16* vv = qkT + 16777216;                // [B, 512, 2048] bf16, 16 MB
  u16* S = vv + 8388608;                   // [B, 2048, 2048] bf16, 64 MB
  u16* wb = S + 33554432;                  // wq|wk|wv|wp bf16, 2 MB
  u16* attnT = hT;                         // alias: hT dead after qk + v GEMMs
  float* out = (float*)d_out;

  cvt_w<<<dim3(1024, 4, 1), 256, 0, stream>>>(wq, wk, wv, wp, wb);
  cvt_bias<<<dim3(4), 256, 0, stream>>>(bq, bk, bqk);
  gn_stats<<<dim3(256), 256, 0, stream>>>(x, stats);
  gn_apply_t<<<dim3(32, 8, 8), 256, 0, stream>>>(x, stats, gs, gb, hT);

  // qkT[r][o] = sum_c hT[r][c]*Wqk[o][c] + bqk[o];  per-b tiles 8m x 4n = 32 -> 256 blocks
  gemm6<0, 256, 256><<<dim3(256), 512, 0, stream>>>(
      hT, wb, qkT, bqk, nullptr, 512, 512, 512, 1024, /*GX*/4, /*mOffB*/2048, 0, 0, 0, 0, 0.f);
  // v[b][o][n] = sum_c Wv[o][c]*hT[b][n][c] + bv[o];  per-b 2m x 16n = 32 -> 256 blocks
  gemm6<1, 256, 128><<<dim3(256), 512, 0, stream>>>(
      wb + 524288, hT, vv, bv, nullptr, 512, 512, 512, 2048, 16, 0, 0, 1048576, 1048576, 0, 0.f);
  // S[b][i][j] = scale * sum_c q[b][i][c]*k[b][j][c];  per-b 8m x 8n = 64 -> 512 blocks
  gemm6<2, 256, 256><<<dim3(512), 512, 0, stream>>>(
      qkT, qkT + 512, S, nullptr, nullptr, 512, 1024, 1024, 2048, 8, 0, 2097152, 2097152,
      4194304, 0, 0.04419417382415922f);
  softmax_rows<<<dim3(16384), 256, 0, stream>>>(S);
  // attnT[b][i][c] = sum_j P[b][i][j]*v[b][c][j];  per-b 8m x 4n = 32 -> 256 blocks
  gemm6<3, 256, 128><<<dim3(256), 512, 0, stream>>>(
      S, vv, attnT, nullptr, nullptr, 2048, 2048, 2048, 512, 4, 0, 4194304, 1048576,
      1048576, 0, 0.f);
  // out[b][o][n] = sum_c Wp[o][c]*attnT[b][n][c] + bp[o] + x[b][o][n];  per-b 2m x 16n = 32 -> 256
  gemm6<4, 256, 128><<<dim3(256), 512, 0, stream>>>(
      wb + 786432, attnT, out, bp, x, 512, 512, 512, 2048, 16, 0, 0, 1048576, 1048576,
      1048576, 0.f);
}